// Round 3
// baseline (385.600 us; speedup 1.0000x reference)
//
#include <hip/hip_runtime.h>
#include <cstdint>

#define S_DIM 128
#define L_DIM 512
#define INimD 256
#define OUTF  128

typedef __bf16 bf16x8 __attribute__((ext_vector_type(8)));
typedef __bf16 bf16x4 __attribute__((ext_vector_type(4)));
typedef float  f32x16 __attribute__((ext_vector_type(16)));

__device__ __forceinline__ unsigned short f2bf(float f) {
  // round-to-nearest-even f32 -> bf16 (inputs are finite/normal here)
  unsigned int u = __float_as_uint(f);
  u = (u + 0x7fffu + ((u >> 16) & 1u)) >> 16;
  return (unsigned short)u;
}

__device__ __forceinline__ void gload_lds16(const void* gsrc, void* ldst) {
  __builtin_amdgcn_global_load_lds(
      (const __attribute__((address_space(1))) unsigned int*)gsrc,
      (__attribute__((address_space(3))) unsigned int*)ldst, 16, 0, 0);
}

// ---------------- kernel P: fused prep (norm tiles | W2->WB | w_proj->WP) ----
// blocks 0..1023   : recip[i,j] = 1/(mask^T mask + .001), 16x16 tile each
// blocks 1024..1087: W2 -> bf16 pre-swizzled B-fragments (WB)
// blocks 1088..1095: w_proj -> bf16 B-fragments (WP)
__global__ __launch_bounds__(256) void k_prep(
    const float* __restrict__ mask, float* __restrict__ recip,
    const float* __restrict__ W, unsigned short* __restrict__ WB,
    const float* __restrict__ w, unsigned short* __restrict__ WP)
{
  __shared__ float mi[128][16];
  __shared__ float mj[128][16];
  const int t = blockIdx.x;
  if (t < 1024) {
    const int i0 = (t >> 5) * 16, j0 = (t & 31) * 16;
    for (int idx = threadIdx.x; idx < 2048; idx += 256) {
      const int s = idx >> 4, cc = idx & 15;
      mi[s][cc] = mask[(size_t)s * L_DIM + i0 + cc];
      mj[s][cc] = mask[(size_t)s * L_DIM + j0 + cc];
    }
    __syncthreads();
    const int ti = threadIdx.x >> 4, tj = threadIdx.x & 15;
    float acc = 0.f;
#pragma unroll 8
    for (int s = 0; s < 128; ++s) acc += mi[s][ti] * mj[s][tj];
    recip[(size_t)(i0 + ti) * L_DIM + j0 + tj] = 1.0f / (acc + 0.001f);
  } else if (t < 1088) {
    const int gid = (t - 1024) * 256 + threadIdx.x;   // 0..16383
    const int ln = gid & 63;
    const int ftkt = gid >> 6;                        // 0..255
    const int ft = ftkt & 3, kt = ftkt >> 2;
    const int f  = ft * 32 + (ln & 31);
    const int kb = kt * 16 + (ln >> 5) * 8;
#pragma unroll
    for (int jj = 0; jj < 8; ++jj) {
      const int k = kb + jj;                          // k = d*32 + e
      WB[(size_t)gid * 8 + jj] = f2bf(W[(size_t)k * OUTF + f]);
    }
  } else {
    const int gid = (t - 1088) * 256 + threadIdx.x;   // 0..2047
    const int ln = gid & 63, tt = gid >> 6;           // tt = kt*2+nt
    const int nt = tt & 1, kt = tt >> 1;
    const int j  = nt * 32 + (ln & 31);
    const int k0 = kt * 16 + (ln >> 5) * 8;
#pragma unroll
    for (int jj = 0; jj < 8; ++jj)
      WP[(size_t)gid * 8 + jj] = f2bf(w[(size_t)j * INimD + k0 + jj]);
  }
}

// ---------------- kernel 1: LayerNorm + MFMA projection + transpose ---------
__global__ __launch_bounds__(256) void k_lnproj(
    const float* __restrict__ x, const float* __restrict__ mask,
    const unsigned short* __restrict__ WP, const float* __restrict__ b,
    unsigned short* __restrict__ l_t, unsigned short* __restrict__ r_t)
{
  __shared__ unsigned short smem[128 * 256];  // 64KB: xhat bf16 (XOR-swizzled rows); reused for act
  __shared__ float msk[128];
  const int tid = threadIdx.x;
  const int wv = tid >> 6, lane = tid & 63;
  const int half = lane >> 5, ln = lane & 31;
  const int l = blockIdx.x;

  if (tid < 128) msk[tid] = mask[(size_t)tid * L_DIM + l];

  // ---- LN with software-pipelined loads: batch bi+1 in flight over reduce(bi)
  float4 v[4];
#pragma unroll
  for (int q = 0; q < 4; ++q)
    v[q] = ((const float4*)(x + ((size_t)(wv * 32 + q) * L_DIM + l) * INimD))[lane];
  for (int bi = 0; bi < 8; ++bi) {
    const int r0 = wv * 32 + bi * 4;
    float4 vn[4];
    if (bi < 7) {
#pragma unroll
      for (int q = 0; q < 4; ++q)
        vn[q] = ((const float4*)(x + ((size_t)(r0 + 4 + q) * L_DIM + l) * INimD))[lane];
    }
#pragma unroll
    for (int q = 0; q < 4; ++q) {
      float sm = v[q].x + v[q].y + v[q].z + v[q].w;
      float sq = v[q].x*v[q].x + v[q].y*v[q].y + v[q].z*v[q].z + v[q].w*v[q].w;
#pragma unroll
      for (int off = 32; off > 0; off >>= 1) {
        sm += __shfl_xor(sm, off);
        sq += __shfl_xor(sq, off);
      }
      const float mu  = sm * (1.0f / 256.0f);
      const float var = sq * (1.0f / 256.0f) - mu * mu;
      const float rs  = rsqrtf(var + 1e-5f);
      const int r = r0 + q;
      ushort4 hp;
      hp.x = f2bf((v[q].x - mu) * rs);
      hp.y = f2bf((v[q].y - mu) * rs);
      hp.z = f2bf((v[q].z - mu) * rs);
      hp.w = f2bf((v[q].w - mu) * rs);
      const int col = (lane * 4) ^ ((r & 7) << 3);     // u16 units
      *(ushort4*)&smem[r * 256 + col] = hp;
    }
#pragma unroll
    for (int q = 0; q < 4; ++q) v[q] = vn[q];
  }
  __syncthreads();

  // ---- projection: act[s,:] = xhat[s,:] @ w^T via 32x32x16 bf16 MFMA
  f32x16 acc0, acc1;
#pragma unroll
  for (int q = 0; q < 16; ++q) { acc0[q] = 0.f; acc1[q] = 0.f; }
  const int ar = wv * 32 + ln;
#pragma unroll
  for (int kt = 0; kt < 16; ++kt) {
    const int col = (kt * 16 + half * 8) ^ ((ln & 7) << 3);
    bf16x8 a  = *(const bf16x8*)&smem[ar * 256 + col];
    bf16x8 b0 = *(const bf16x8*)(WP + ((size_t)((kt * 2 + 0) * 64 + lane)) * 8);
    bf16x8 b1 = *(const bf16x8*)(WP + ((size_t)((kt * 2 + 1) * 64 + lane)) * 8);
    acc0 = __builtin_amdgcn_mfma_f32_32x32x16_bf16(a, b0, acc0, 0, 0, 0);
    acc1 = __builtin_amdgcn_mfma_f32_32x32x16_bf16(a, b1, acc1, 0, 0, 0);
  }
  __syncthreads();

  // ---- epilogue: C layout col=ln&31, row=(reg&3)+8*(reg>>2)+4*half
  unsigned short (*act)[136] = (unsigned short(*)[136])smem;
  const float bj0 = b[ln];
  const float bj1 = b[32 + ln];
#pragma unroll
  for (int nt = 0; nt < 2; ++nt) {
    const f32x16 a = nt ? acc1 : acc0;
    const float bj = nt ? bj1 : bj0;
    const int j = nt * 32 + ln;
#pragma unroll
    for (int g = 0; g < 4; ++g) {
      const int s0 = wv * 32 + g * 8 + half * 4;
      ushort4 p;
      p.x = f2bf((a[g*4+0] + bj) * msk[s0+0]);
      p.y = f2bf((a[g*4+1] + bj) * msk[s0+1]);
      p.z = f2bf((a[g*4+2] + bj) * msk[s0+2]);
      p.w = f2bf((a[g*4+3] + bj) * msk[s0+3]);
      *(ushort4*)&act[j][s0] = p;
    }
  }
  __syncthreads();

  const int d = tid >> 2, c = (tid & 3) * 32;   // d in 0..63, c in {0,32,64,96}
  uint4 outv[4];
  ushort4* pv = (ushort4*)outv;
#pragma unroll
  for (int q = 0; q < 8; ++q) pv[q] = *(ushort4*)&act[d][c + q * 4];
  unsigned short* dst = (d < 32)
      ? (l_t + ((size_t)l * 32 + d) * S_DIM + c)
      : (r_t + ((size_t)l * 32 + (d - 32)) * S_DIM + c);
  ((uint4*)dst)[0] = outv[0];
  ((uint4*)dst)[1] = outv[1];
  ((uint4*)dst)[2] = outv[2];
  ((uint4*)dst)[3] = outv[3];
}

// ---------------- kernel 4: fused pair-GEMM (v3) ----------------------------
// Tile: 16 i x 4 j = 64 pairs per block, f = 128.
// r in registers (A of phase A). l double-buffered in LDS (4-bit XOR swizzle,
// staged via global_load_lds with pre-swizzled source). G round-trips through
// g_lds [2][64][64] with row-permute sigma(pair)=jl*16+ii and 8B-unit XOR
// swizzle (^ row&15): writes AND reads bank-conflict-free (audited).
// Single barrier per K-chunk. 32KB LDS -> 4 blocks/CU.
__global__ __launch_bounds__(256, 4) void k_pair(
    const unsigned short* __restrict__ l_t, const unsigned short* __restrict__ r_t,
    const unsigned short* __restrict__ WB, const float* __restrict__ recip,
    const float* __restrict__ bias, float* __restrict__ out)
{
  __shared__ __align__(16) unsigned short l_lds[2][32][128]; // 16B-granule ^ (row&15)
  __shared__ __align__(16) unsigned short g_lds[2][64][64];  // sigma-row x kl, 8B-unit ^ (row&15)
  const int tid = threadIdx.x;
  const int wv = tid >> 6, lane = tid & 63;
  const int half = lane >> 5, ln = lane & 31;
  const int j0 = blockIdx.x * 4, i0 = blockIdx.y * 16;

  // ---- r A-frags in registers
  bf16x8 rf[8];
#pragma unroll
  for (int s8 = 0; s8 < 8; ++s8)
    rf[s8] = *(const bf16x8*)(r_t + ((size_t)(j0 + wv) * 32 + ln) * S_DIM
                                  + s8 * 16 + half * 8);

  // ---- staging sources for l (pre-swizzled per-lane global addr, 4-bit key)
  const unsigned short* lsrc[2];
#pragma unroll
  for (int t = 0; t < 2; ++t) {
    const int r_ = wv * 8 + t * 4 + (lane >> 4);
    const int gg = lane & 15;
    lsrc[t] = l_t + ((size_t)(i0 + (r_ & 15)) * 32 + (r_ >> 4)) * S_DIM
                  + ((gg ^ (r_ & 15)) * 8);
  }
#pragma unroll
  for (int t = 0; t < 2; ++t)
    gload_lds16(lsrc[t], &l_lds[0][wv * 8 + t * 4][0]);

  f32x16 acc0, acc1;
#pragma unroll
  for (int q = 0; q < 16; ++q) { acc0[q] = 0.f; acc1[q] = 0.f; }

  const int prow = wv * 16 + (ln & 15);  // sigma row this lane writes
  const int dcc  = ln >> 4;              // this lane's dc

  __syncthreads();   // c=0 staging complete

  for (int c = 0; c < 16; ++c) {
    const int cur = c & 1;
    if (c < 15) {
#pragma unroll
      for (int t = 0; t < 2; ++t) {
        lsrc[t] += 256;
        gload_lds16(lsrc[t], &l_lds[cur ^ 1][wv * 8 + t * 4][0]);
      }
    }
    bf16x8 bw[4];
#pragma unroll
    for (int kt = 0; kt < 4; ++kt)
      bw[kt] = *(const bf16x8*)(WB + ((size_t)((c * 4 + kt) * 4 + wv) * 64 + lane) * 8);

    // ---- phase A: G = r . l  (A = r regs, B = l from LDS)
    f32x16 g;
#pragma unroll
    for (int q = 0; q < 16; ++q) g[q] = 0.f;
    __builtin_amdgcn_s_setprio(1);
#pragma unroll
    for (int s8 = 0; s8 < 8; ++s8) {
      const int col = (((s8 * 2 + half) ^ (ln & 15))) * 8;  // swizzled u16 col
      bf16x8 bl = *(const bf16x8*)&l_lds[cur][ln][col];
      g = __builtin_amdgcn_mfma_f32_32x32x16_bf16(rf[s8], bl, g, 0, 0, 0);
    }
    __builtin_amdgcn_s_setprio(0);
    // write G: lane -> sigma row prow; quad q -> u8 unit (8dcc+2q+half)^(prow&15)
    {
      unsigned short* g0 = &g_lds[cur][prow][0];
      const int key = prow & 15;
#pragma unroll
      for (int q = 0; q < 4; ++q) {
        ushort4 hp;
        hp.x = f2bf(g[4*q+0]); hp.y = f2bf(g[4*q+1]);
        hp.z = f2bf(g[4*q+2]); hp.w = f2bf(g[4*q+3]);
        const int u8 = (8 * dcc + 2 * q + half) ^ key;
        *(ushort4*)(g0 + u8 * 4) = hp;
      }
    }
    __syncthreads();   // single barrier: g visible, l[c+1] staged

    // ---- phase B: wave wv owns f-strip [32*wv, 32*wv+32)
    __builtin_amdgcn_s_setprio(1);
#pragma unroll
    for (int kt = 0; kt < 4; ++kt) {
      const int b8 = kt * 4 + 2 * half;
      const int r0_ = ln,     k0 = r0_ & 15;
      const int r1_ = 32 + ln, k1 = r1_ & 15;
      const unsigned short* gp0 = &g_lds[cur][r0_][0];
      const unsigned short* gp1 = &g_lds[cur][r1_][0];
      bf16x4 a0l = *(const bf16x4*)(gp0 + ((b8    ) ^ k0) * 4);
      bf16x4 a0h = *(const bf16x4*)(gp0 + ((b8 + 1) ^ k0) * 4);
      bf16x4 a1l = *(const bf16x4*)(gp1 + ((b8    ) ^ k1) * 4);
      bf16x4 a1h = *(const bf16x4*)(gp1 + ((b8 + 1) ^ k1) * 4);
      bf16x8 a0 = __builtin_shufflevector(a0l, a0h, 0,1,2,3,4,5,6,7);
      bf16x8 a1 = __builtin_shufflevector(a1l, a1h, 0,1,2,3,4,5,6,7);
      acc0 = __builtin_amdgcn_mfma_f32_32x32x16_bf16(a0, bw[kt], acc0, 0, 0, 0);
      acc1 = __builtin_amdgcn_mfma_f32_32x32x16_bf16(a1, bw[kt], acc1, 0, 0, 0);
    }
    __builtin_amdgcn_s_setprio(0);
  }

  // epilogue: D row rr maps to sigma row mt*32+rr -> pair = (rr&15)*4 + mt*2 + (rr>>4)
  const float bi = bias[wv * 32 + ln];
#pragma unroll
  for (int mt = 0; mt < 2; ++mt) {
    const f32x16 a = mt ? acc1 : acc0;
#pragma unroll
    for (int reg = 0; reg < 16; ++reg) {
      const int rr = (reg & 3) + 8 * (reg >> 2) + 4 * half;
      const int p  = (rr & 15) * 4 + mt * 2 + (rr >> 4);
      const int i = i0 + (p >> 2), j = j0 + (p & 3);
      const float val = (a[reg] + bi) * recip[(size_t)i * L_DIM + j];
      out[((size_t)i * L_DIM + j) * OUTF + wv * 32 + ln] = val;
    }
  }
}

extern "C" void kernel_launch(void* const* d_in, const int* in_sizes, int n_in,
                              void* d_out, int out_size, void* d_ws, size_t ws_size,
                              hipStream_t stream) {
  const float* x    = (const float*)d_in[0];   // node_repr (128,512,256)
  const float* mask = (const float*)d_in[1];   // (128,512)
  const float* w    = (const float*)d_in[2];   // w_proj (64,256)
  const float* b    = (const float*)d_in[3];   // b_proj (64)
  const float* W    = (const float*)d_in[4];   // out_weights (32,32,128)
  const float* bias = (const float*)d_in[5];   // out_bias (128)
  float* out = (float*)d_out;

  char* ws = (char*)d_ws;
  unsigned short* l_t = (unsigned short*)ws;                         // 4 MB
  unsigned short* r_t = (unsigned short*)(ws + (4u << 20));          // 4 MB
  unsigned short* WB  = (unsigned short*)(ws + (8u << 20));          // 256 KB
  float* recip = (float*)(ws + (8u << 20) + (512u << 10));           // 1 MB
  unsigned short* WP  = (unsigned short*)(ws + (8u << 20) + (512u << 10) + (1u << 20)); // 32 KB

  hipLaunchKernelGGL(k_prep,   dim3(1096),     dim3(256), 0, stream, mask, recip, W, WB, w, WP);
  hipLaunchKernelGGL(k_lnproj, dim3(512),      dim3(256), 0, stream, x, mask, WP, b, l_t, r_t);
  hipLaunchKernelGGL(k_pair,   dim3(128, 32),  dim3(256), 0, stream, l_t, r_t, WB, recip, bias, out);
}

// Round 4
// 336.687 us; speedup vs baseline: 1.1453x; 1.1453x over previous
//
#include <hip/hip_runtime.h>
#include <cstdint>

#define S_DIM 128
#define L_DIM 512
#define INimD 256
#define OUTF  128

typedef __bf16 bf16x8 __attribute__((ext_vector_type(8)));
typedef __bf16 bf16x4 __attribute__((ext_vector_type(4)));
typedef float  f32x16 __attribute__((ext_vector_type(16)));

__device__ __forceinline__ unsigned short f2bf(float f) {
  // round-to-nearest-even f32 -> bf16 (inputs are finite/normal here)
  unsigned int u = __float_as_uint(f);
  u = (u + 0x7fffu + ((u >> 16) & 1u)) >> 16;
  return (unsigned short)u;
}

__device__ __forceinline__ void gload_lds16(const void* gsrc, void* ldst) {
  __builtin_amdgcn_global_load_lds(
      (const __attribute__((address_space(1))) unsigned int*)gsrc,
      (__attribute__((address_space(3))) unsigned int*)ldst, 16, 0, 0);
}

// ---------------- kernel P: fused prep (norm tiles | W2->WB | w_proj->WP) ----
// blocks 0..1023   : recip[i,j] = 1/(mask^T mask + .001), 16x16 tile each
// blocks 1024..1087: W2 -> bf16 pre-swizzled B-fragments (WB)
// blocks 1088..1095: w_proj -> bf16 B-fragments (WP)
__global__ __launch_bounds__(256) void k_prep(
    const float* __restrict__ mask, float* __restrict__ recip,
    const float* __restrict__ W, unsigned short* __restrict__ WB,
    const float* __restrict__ w, unsigned short* __restrict__ WP)
{
  __shared__ float mi[128][16];
  __shared__ float mj[128][16];
  const int t = blockIdx.x;
  if (t < 1024) {
    const int i0 = (t >> 5) * 16, j0 = (t & 31) * 16;
    for (int idx = threadIdx.x; idx < 2048; idx += 256) {
      const int s = idx >> 4, cc = idx & 15;
      mi[s][cc] = mask[(size_t)s * L_DIM + i0 + cc];
      mj[s][cc] = mask[(size_t)s * L_DIM + j0 + cc];
    }
    __syncthreads();
    const int ti = threadIdx.x >> 4, tj = threadIdx.x & 15;
    float acc = 0.f;
#pragma unroll 8
    for (int s = 0; s < 128; ++s) acc += mi[s][ti] * mj[s][tj];
    recip[(size_t)(i0 + ti) * L_DIM + j0 + tj] = 1.0f / (acc + 0.001f);
  } else if (t < 1088) {
    const int gid = (t - 1024) * 256 + threadIdx.x;   // 0..16383
    const int ln = gid & 63;
    const int ftkt = gid >> 6;                        // 0..255
    const int ft = ftkt & 3, kt = ftkt >> 2;
    const int f  = ft * 32 + (ln & 31);
    const int kb = kt * 16 + (ln >> 5) * 8;
#pragma unroll
    for (int jj = 0; jj < 8; ++jj) {
      const int k = kb + jj;                          // k = d*32 + e
      WB[(size_t)gid * 8 + jj] = f2bf(W[(size_t)k * OUTF + f]);
    }
  } else {
    const int gid = (t - 1088) * 256 + threadIdx.x;   // 0..2047
    const int ln = gid & 63, tt = gid >> 6;           // tt = kt*2+nt
    const int nt = tt & 1, kt = tt >> 1;
    const int j  = nt * 32 + (ln & 31);
    const int k0 = kt * 16 + (ln >> 5) * 8;
#pragma unroll
    for (int jj = 0; jj < 8; ++jj)
      WP[(size_t)gid * 8 + jj] = f2bf(w[(size_t)j * INimD + k0 + jj]);
  }
}

// ---------------- kernel 1: LayerNorm + MFMA projection + transpose ---------
__global__ __launch_bounds__(256) void k_lnproj(
    const float* __restrict__ x, const float* __restrict__ mask,
    const unsigned short* __restrict__ WP, const float* __restrict__ b,
    unsigned short* __restrict__ l_t, unsigned short* __restrict__ r_t)
{
  __shared__ unsigned short smem[128 * 256];  // 64KB: xhat bf16 (XOR-swizzled rows); reused for act
  __shared__ float msk[128];
  const int tid = threadIdx.x;
  const int wv = tid >> 6, lane = tid & 63;
  const int half = lane >> 5, ln = lane & 31;
  const int l = blockIdx.x;

  if (tid < 128) msk[tid] = mask[(size_t)tid * L_DIM + l];

  // ---- LN with software-pipelined loads: batch bi+1 in flight over reduce(bi)
  float4 v[4];
#pragma unroll
  for (int q = 0; q < 4; ++q)
    v[q] = ((const float4*)(x + ((size_t)(wv * 32 + q) * L_DIM + l) * INimD))[lane];
  for (int bi = 0; bi < 8; ++bi) {
    const int r0 = wv * 32 + bi * 4;
    float4 vn[4];
    if (bi < 7) {
#pragma unroll
      for (int q = 0; q < 4; ++q)
        vn[q] = ((const float4*)(x + ((size_t)(r0 + 4 + q) * L_DIM + l) * INimD))[lane];
    }
#pragma unroll
    for (int q = 0; q < 4; ++q) {
      float sm = v[q].x + v[q].y + v[q].z + v[q].w;
      float sq = v[q].x*v[q].x + v[q].y*v[q].y + v[q].z*v[q].z + v[q].w*v[q].w;
#pragma unroll
      for (int off = 32; off > 0; off >>= 1) {
        sm += __shfl_xor(sm, off);
        sq += __shfl_xor(sq, off);
      }
      const float mu  = sm * (1.0f / 256.0f);
      const float var = sq * (1.0f / 256.0f) - mu * mu;
      const float rs  = rsqrtf(var + 1e-5f);
      const int r = r0 + q;
      ushort4 hp;
      hp.x = f2bf((v[q].x - mu) * rs);
      hp.y = f2bf((v[q].y - mu) * rs);
      hp.z = f2bf((v[q].z - mu) * rs);
      hp.w = f2bf((v[q].w - mu) * rs);
      const int col = (lane * 4) ^ ((r & 7) << 3);     // u16 units
      *(ushort4*)&smem[r * 256 + col] = hp;
    }
#pragma unroll
    for (int q = 0; q < 4; ++q) v[q] = vn[q];
  }
  __syncthreads();

  // ---- projection: act[s,:] = xhat[s,:] @ w^T via 32x32x16 bf16 MFMA
  f32x16 acc0, acc1;
#pragma unroll
  for (int q = 0; q < 16; ++q) { acc0[q] = 0.f; acc1[q] = 0.f; }
  const int ar = wv * 32 + ln;
#pragma unroll
  for (int kt = 0; kt < 16; ++kt) {
    const int col = (kt * 16 + half * 8) ^ ((ln & 7) << 3);
    bf16x8 a  = *(const bf16x8*)&smem[ar * 256 + col];
    bf16x8 b0 = *(const bf16x8*)(WP + ((size_t)((kt * 2 + 0) * 64 + lane)) * 8);
    bf16x8 b1 = *(const bf16x8*)(WP + ((size_t)((kt * 2 + 1) * 64 + lane)) * 8);
    acc0 = __builtin_amdgcn_mfma_f32_32x32x16_bf16(a, b0, acc0, 0, 0, 0);
    acc1 = __builtin_amdgcn_mfma_f32_32x32x16_bf16(a, b1, acc1, 0, 0, 0);
  }
  __syncthreads();

  // ---- epilogue: C layout col=ln&31, row=(reg&3)+8*(reg>>2)+4*half
  unsigned short (*act)[136] = (unsigned short(*)[136])smem;
  const float bj0 = b[ln];
  const float bj1 = b[32 + ln];
#pragma unroll
  for (int nt = 0; nt < 2; ++nt) {
    const f32x16 a = nt ? acc1 : acc0;
    const float bj = nt ? bj1 : bj0;
    const int j = nt * 32 + ln;
#pragma unroll
    for (int g = 0; g < 4; ++g) {
      const int s0 = wv * 32 + g * 8 + half * 4;
      ushort4 p;
      p.x = f2bf((a[g*4+0] + bj) * msk[s0+0]);
      p.y = f2bf((a[g*4+1] + bj) * msk[s0+1]);
      p.z = f2bf((a[g*4+2] + bj) * msk[s0+2]);
      p.w = f2bf((a[g*4+3] + bj) * msk[s0+3]);
      *(ushort4*)&act[j][s0] = p;
    }
  }
  __syncthreads();

  const int d = tid >> 2, c = (tid & 3) * 32;   // d in 0..63, c in {0,32,64,96}
  uint4 outv[4];
  ushort4* pv = (ushort4*)outv;
#pragma unroll
  for (int q = 0; q < 8; ++q) pv[q] = *(ushort4*)&act[d][c + q * 4];
  unsigned short* dst = (d < 32)
      ? (l_t + ((size_t)l * 32 + d) * S_DIM + c)
      : (r_t + ((size_t)l * 32 + (d - 32)) * S_DIM + c);
  ((uint4*)dst)[0] = outv[0];
  ((uint4*)dst)[1] = outv[1];
  ((uint4*)dst)[2] = outv[2];
  ((uint4*)dst)[3] = outv[3];
}

// ---------------- kernel 4: fused pair-GEMM (v4 = v3 swizzles, v2 reg budget)
// Tile: 16 i x 4 j = 64 pairs per block, f = 128.
// r in registers (A of phase A). l double-buffered in LDS (4-bit XOR swizzle,
// staged via global_load_lds with pre-swizzled source). G round-trips through
// g_lds [2][64][64] with row-permute sigma(pair)=jl*16+ii and 8B-unit XOR
// swizzle (^ row&15): writes AND reads bank-conflict-free (verified: 0 in HW).
// Single barrier per K-chunk. launch_bounds(256,3): 170-reg budget -> NO SPILL
// (bounds(256,4) spilled: +50MB fetch / +84MB write of scratch, -25% MfmaUtil).
__global__ __launch_bounds__(256, 3) void k_pair(
    const unsigned short* __restrict__ l_t, const unsigned short* __restrict__ r_t,
    const unsigned short* __restrict__ WB, const float* __restrict__ recip,
    const float* __restrict__ bias, float* __restrict__ out)
{
  __shared__ __align__(16) unsigned short l_lds[2][32][128]; // 16B-granule ^ (row&15)
  __shared__ __align__(16) unsigned short g_lds[2][64][64];  // sigma-row x kl, 8B-unit ^ (row&15)
  const int tid = threadIdx.x;
  const int wv = tid >> 6, lane = tid & 63;
  const int half = lane >> 5, ln = lane & 31;
  const int j0 = blockIdx.x * 4, i0 = blockIdx.y * 16;

  // ---- r A-frags in registers
  bf16x8 rf[8];
#pragma unroll
  for (int s8 = 0; s8 < 8; ++s8)
    rf[s8] = *(const bf16x8*)(r_t + ((size_t)(j0 + wv) * 32 + ln) * S_DIM
                                  + s8 * 16 + half * 8);

  // ---- staging sources for l (pre-swizzled per-lane global addr, 4-bit key)
  const unsigned short* lsrc[2];
#pragma unroll
  for (int t = 0; t < 2; ++t) {
    const int r_ = wv * 8 + t * 4 + (lane >> 4);
    const int gg = lane & 15;
    lsrc[t] = l_t + ((size_t)(i0 + (r_ & 15)) * 32 + (r_ >> 4)) * S_DIM
                  + ((gg ^ (r_ & 15)) * 8);
  }
#pragma unroll
  for (int t = 0; t < 2; ++t)
    gload_lds16(lsrc[t], &l_lds[0][wv * 8 + t * 4][0]);

  f32x16 acc0, acc1;
#pragma unroll
  for (int q = 0; q < 16; ++q) { acc0[q] = 0.f; acc1[q] = 0.f; }

  const int prow = wv * 16 + (ln & 15);  // sigma row this lane writes
  const int dcc  = ln >> 4;              // this lane's dc

  __syncthreads();   // c=0 staging complete

  for (int c = 0; c < 16; ++c) {
    const int cur = c & 1;
    if (c < 15) {
#pragma unroll
      for (int t = 0; t < 2; ++t) {
        lsrc[t] += 256;
        gload_lds16(lsrc[t], &l_lds[cur ^ 1][wv * 8 + t * 4][0]);
      }
    }
    bf16x8 bw[4];
#pragma unroll
    for (int kt = 0; kt < 4; ++kt)
      bw[kt] = *(const bf16x8*)(WB + ((size_t)((c * 4 + kt) * 4 + wv) * 64 + lane) * 8);

    // ---- phase A: G = r . l  (A = r regs, B = l from LDS)
    f32x16 g;
#pragma unroll
    for (int q = 0; q < 16; ++q) g[q] = 0.f;
    __builtin_amdgcn_s_setprio(1);
#pragma unroll
    for (int s8 = 0; s8 < 8; ++s8) {
      const int col = (((s8 * 2 + half) ^ (ln & 15))) * 8;  // swizzled u16 col
      bf16x8 bl = *(const bf16x8*)&l_lds[cur][ln][col];
      g = __builtin_amdgcn_mfma_f32_32x32x16_bf16(rf[s8], bl, g, 0, 0, 0);
    }
    __builtin_amdgcn_s_setprio(0);
    // write G: lane -> sigma row prow; quad q -> u8 unit (8dcc+2q+half)^(prow&15)
    {
      unsigned short* g0 = &g_lds[cur][prow][0];
      const int key = prow & 15;
#pragma unroll
      for (int q = 0; q < 4; ++q) {
        ushort4 hp;
        hp.x = f2bf(g[4*q+0]); hp.y = f2bf(g[4*q+1]);
        hp.z = f2bf(g[4*q+2]); hp.w = f2bf(g[4*q+3]);
        const int u8 = (8 * dcc + 2 * q + half) ^ key;
        *(ushort4*)(g0 + u8 * 4) = hp;
      }
    }
    __syncthreads();   // single barrier: g visible, l[c+1] staged

    // ---- phase B: wave wv owns f-strip [32*wv, 32*wv+32)
    __builtin_amdgcn_s_setprio(1);
#pragma unroll
    for (int kt = 0; kt < 4; ++kt) {
      const int b8 = kt * 4 + 2 * half;
      const int r0_ = ln,     k0 = r0_ & 15;
      const int r1_ = 32 + ln, k1 = r1_ & 15;
      const unsigned short* gp0 = &g_lds[cur][r0_][0];
      const unsigned short* gp1 = &g_lds[cur][r1_][0];
      bf16x4 a0l = *(const bf16x4*)(gp0 + ((b8    ) ^ k0) * 4);
      bf16x4 a0h = *(const bf16x4*)(gp0 + ((b8 + 1) ^ k0) * 4);
      bf16x4 a1l = *(const bf16x4*)(gp1 + ((b8    ) ^ k1) * 4);
      bf16x4 a1h = *(const bf16x4*)(gp1 + ((b8 + 1) ^ k1) * 4);
      bf16x8 a0 = __builtin_shufflevector(a0l, a0h, 0,1,2,3,4,5,6,7);
      bf16x8 a1 = __builtin_shufflevector(a1l, a1h, 0,1,2,3,4,5,6,7);
      acc0 = __builtin_amdgcn_mfma_f32_32x32x16_bf16(a0, bw[kt], acc0, 0, 0, 0);
      acc1 = __builtin_amdgcn_mfma_f32_32x32x16_bf16(a1, bw[kt], acc1, 0, 0, 0);
    }
    __builtin_amdgcn_s_setprio(0);
  }

  // epilogue: D row rr maps to sigma row mt*32+rr -> pair = (rr&15)*4 + mt*2 + (rr>>4)
  const float bi = bias[wv * 32 + ln];
#pragma unroll
  for (int mt = 0; mt < 2; ++mt) {
    const f32x16 a = mt ? acc1 : acc0;
#pragma unroll
    for (int reg = 0; reg < 16; ++reg) {
      const int rr = (reg & 3) + 8 * (reg >> 2) + 4 * half;
      const int p  = (rr & 15) * 4 + mt * 2 + (rr >> 4);
      const int i = i0 + (p >> 2), j = j0 + (p & 3);
      const float val = (a[reg] + bi) * recip[(size_t)i * L_DIM + j];
      out[((size_t)i * L_DIM + j) * OUTF + wv * 32 + ln] = val;
    }
  }
}

extern "C" void kernel_launch(void* const* d_in, const int* in_sizes, int n_in,
                              void* d_out, int out_size, void* d_ws, size_t ws_size,
                              hipStream_t stream) {
  const float* x    = (const float*)d_in[0];   // node_repr (128,512,256)
  const float* mask = (const float*)d_in[1];   // (128,512)
  const float* w    = (const float*)d_in[2];   // w_proj (64,256)
  const float* b    = (const float*)d_in[3];   // b_proj (64)
  const float* W    = (const float*)d_in[4];   // out_weights (32,32,128)
  const float* bias = (const float*)d_in[5];   // out_bias (128)
  float* out = (float*)d_out;

  char* ws = (char*)d_ws;
  unsigned short* l_t = (unsigned short*)ws;                         // 4 MB
  unsigned short* r_t = (unsigned short*)(ws + (4u << 20));          // 4 MB
  unsigned short* WB  = (unsigned short*)(ws + (8u << 20));          // 256 KB
  float* recip = (float*)(ws + (8u << 20) + (512u << 10));           // 1 MB
  unsigned short* WP  = (unsigned short*)(ws + (8u << 20) + (512u << 10) + (1u << 20)); // 32 KB

  hipLaunchKernelGGL(k_prep,   dim3(1096),     dim3(256), 0, stream, mask, recip, W, WB, w, WP);
  hipLaunchKernelGGL(k_lnproj, dim3(512),      dim3(256), 0, stream, x, mask, WP, b, l_t, r_t);
  hipLaunchKernelGGL(k_pair,   dim3(128, 32),  dim3(256), 0, stream, l_t, r_t, WB, recip, bias, out);
}